// Round 6
// baseline (126.945 us; speedup 1.0000x reference)
//
#include <hip/hip_runtime.h>
#include <stdint.h>

#define D_DIM 1024
#define N_DIM 65536
#define Q_DIM 2048
#define K_DIM 3

#define NBLK  256            // one block per CU
#define TPB   1024           // 16 waves
#define NMAC  8              // 8 macros x 32 cols = 256 cols per block
#define RING  5              // ring of 16-KB raw quarter slots
#define NQT   64             // quarters total (NMAC * 8)

// LDS map (dynamic):
#define RING_OFF  0          // 5 x 16384 B raw f32 quarters
#define TAB_OFF   81920      // bf16 table [1024 rows][32 cols] = 65536 B, granule-swizzled
#define SCR_OFF   147456     // per-wave reduce scratch 16 x 256 B = 4096 B
#define LDS_TOTAL 151552

#define VMCNT0() asm volatile("s_waitcnt vmcnt(0)" ::: "memory")
#define LGKM0()  asm volatile("s_waitcnt lgkmcnt(0)" ::: "memory")
#define SCHED0() __builtin_amdgcn_sched_barrier(0)
#define SBAR()   __builtin_amdgcn_s_barrier()

typedef const __attribute__((address_space(1))) uint32_t  glb_u32;
typedef __attribute__((address_space(3))) uint32_t        lds_u32;

__device__ __forceinline__ void vmwait(int n) {   // n must be compile-time constant
    switch (n) {
    case 0: asm volatile("s_waitcnt vmcnt(0)" ::: "memory"); break;
    case 1: asm volatile("s_waitcnt vmcnt(1)" ::: "memory"); break;
    case 2: asm volatile("s_waitcnt vmcnt(2)" ::: "memory"); break;
    case 3: asm volatile("s_waitcnt vmcnt(3)" ::: "memory"); break;
    default: asm volatile("s_waitcnt vmcnt(4)" ::: "memory"); break;
    }
}

// round-to-nearest-even f32 -> bf16 (positive normal probs)
__device__ __forceinline__ uint32_t f2bf(float f) {
    uint32_t u = __float_as_uint(f);
    return (u + 0x7fffu + ((u >> 16) & 1u)) >> 16;
}
__device__ __forceinline__ float blo(uint32_t u) { return __uint_as_float(u << 16); }
__device__ __forceinline__ float bhi(uint32_t u) { return __uint_as_float(u & 0xffff0000u); }

// sum over the 4 lanes of a quad via DPP quad_perm (VALU pipe, no LDS)
__device__ __forceinline__ float quad_sum(float x) {
    float t = __uint_as_float(__builtin_amdgcn_update_dpp(
        0, (int)__float_as_uint(x), 0xB1, 0xf, 0xf, true));   // xor 1
    x += t;
    t = __uint_as_float(__builtin_amdgcn_update_dpp(
        0, (int)__float_as_uint(x), 0x4E, 0xf, 0xf, true));   // xor 2
    return x + t;
}

// DMA quarter q into ring slot rs. Quarter = strip (16 cols, 64 B/row) x 256
// rows. Strip j of block b sits at byte pos j*16384 + ((b+37j)&255)*64 in each
// row: global bijection over all 64-B strips, spreading each block's traffic
// across 12-16 interleave positions for any pow2 channel granule <= 2 KB.
// Wave w stages rows w*16..+15 as ONE inst (4 lanes x 16 B per 64-B row).
__device__ __forceinline__ void stage_q(const float* __restrict__ W, char* smem,
                                        int q, int rs, int bid, int w, int l) {
    const int m = q >> 3, qq = q & 7;
    const int s = qq >> 2, slab = qq & 3;
    const int j = 2 * m + s;
    const int colb = j * 16384 + ((bid + 37 * j) & 255) * 64;
    const int row = slab * 256 + w * 16 + (l >> 2);
    const char* src = (const char*)W + ((size_t)row << 18) + colb + (l & 3) * 16;
    __builtin_amdgcn_global_load_lds((glb_u32*)src,
        (lds_u32*)(smem + RING_OFF + rs * 16384 + w * 1024 + l * 16), 16, 0, 0);
}

// fused softmax: exp once, DPP quad-reduce + scratch combine, pack, table write
__device__ __forceinline__ void process_q(const float* __restrict__ W, char* smem,
                                          int q, int rs, int bid, int w, int l) {
    const int qq = q & 7;
    const int s = qq >> 2, slab = qq & 3;
    const int r = l & 15, c = l >> 4;
    const char* base = smem + RING_OFF + rs * 16384 + w * 1024;

    const float4 raw = *(const float4*)(base + r * 64 + c * 16);
    const float e0 = __expf(raw.x), e1 = __expf(raw.y);
    const float e2 = __expf(raw.z), e3 = __expf(raw.w);
    // quad = 4 consecutive rows, same c -> quad_sum gives 4-row col partials
    const float p0 = quad_sum(e0), p1 = quad_sum(e1);
    const float p2 = quad_sum(e2), p3 = quad_sum(e3);
    if ((l & 3) == 0)
        *(float4*)(smem + SCR_OFF + w * 256 + ((l >> 2) & 3) * 64 + c * 16)
            = make_float4(p0, p1, p2, p3);
    LGKM0();   // wave-local scratch visible
    const float4 t0 = *(const float4*)(smem + SCR_OFF + w * 256 + 0 * 64 + c * 16);
    const float4 t1 = *(const float4*)(smem + SCR_OFF + w * 256 + 1 * 64 + c * 16);
    const float4 t2 = *(const float4*)(smem + SCR_OFF + w * 256 + 2 * 64 + c * 16);
    const float4 t3 = *(const float4*)(smem + SCR_OFF + w * 256 + 3 * 64 + c * 16);
    const float r0 = __builtin_amdgcn_rcpf(t0.x + t1.x + t2.x + t3.x);
    const float r1 = __builtin_amdgcn_rcpf(t0.y + t1.y + t2.y + t3.y);
    const float r2 = __builtin_amdgcn_rcpf(t0.z + t1.z + t2.z + t3.z);
    const float r3 = __builtin_amdgcn_rcpf(t0.w + t1.w + t2.w + t3.w);

    uint2 pk;
    pk.x = f2bf(e0 * r0) | (f2bf(e1 * r1) << 16);
    pk.y = f2bf(e2 * r2) | (f2bf(e3 * r3) << 16);
    const int rt = slab * 256 + w * 16 + r;
    const int g  = s * 2 + (c >> 1);
    *(uint2*)(smem + TAB_OFF + rt * 64 + ((g ^ ((rt >> 1) & 3)) << 4) + (c & 1) * 8) = pk;
}

template<bool ATOMIC>
__global__ __launch_bounds__(TPB, 4) void rap_main(const float* __restrict__ W,
                                                   const int* __restrict__ qidx,
                                                   float* __restrict__ outp) {
    extern __shared__ char smem[];
    const int tid = threadIdx.x;
    const int bid = blockIdx.x;
    const int w = tid >> 6, l = tid & 63;

    // ---- per-thread query constants (2 queries/thread) ----
    const int q0 = tid * 2;
    int baseb[2][K_DIM];   // d*64 : byte base of table row
    int swzb[2][K_DIM];    // ((d>>1)&3)<<4 : granule XOR key in bytes
#pragma unroll
    for (int qq = 0; qq < 2; ++qq) {
#pragma unroll
        for (int k = 0; k < K_DIM; ++k) {
            const int d = qidx[(q0 + qq) * K_DIM + k];
            baseb[qq][k] = d << 6;
            swzb[qq][k]  = ((d >> 1) & 3) << 4;
        }
    }

    float acc0 = 0.f, acc1 = 0.f;

    // drain setup loads so vmcnt counts only stage DMAs, then fill the ring
    VMCNT0(); SCHED0();
#pragma unroll
    for (int q = 0; q < RING; ++q) stage_q(W, smem, q, q, bid, w, l);

    int rs = 0;
    for (int m = 0; m < NMAC; ++m) {
#pragma unroll
        for (int qq = 0; qq < 8; ++qq) {
            const int q = m * 8 + qq;
            // gate: quarter q arrived (FIFO vmcnt); tail tightens to 0
            if (m != NMAC - 1) vmwait(4);
            else               vmwait(qq >= 4 ? 7 - qq : 4);
            SCHED0();

            process_q(W, smem, q, rs, bid, w, l);
            LGKM0(); SCHED0();   // raw reads retired -> slot free to refill

            if (q + RING < NQT) stage_q(W, smem, q + RING, rs, bid, w, l);
            rs = (rs == RING - 1) ? 0 : rs + 1;
        }

        LGKM0(); SCHED0(); SBAR(); SCHED0();   // table published

        // ---- compute: 2 queries x 4 granules x 8 cols (verbatim R5) ----
#pragma unroll
        for (int g16 = 0; g16 < 4; ++g16) {
            const int gb = g16 << 4;
            {
                const uint4 va = *(const uint4*)(smem + TAB_OFF + baseb[0][0] + (gb ^ swzb[0][0]));
                const uint4 vb = *(const uint4*)(smem + TAB_OFF + baseb[0][1] + (gb ^ swzb[0][1]));
                const uint4 vc = *(const uint4*)(smem + TAB_OFF + baseb[0][2] + (gb ^ swzb[0][2]));
                acc0 = fmaf(blo(va.x) * blo(vb.x), blo(vc.x), acc0);
                acc0 = fmaf(bhi(va.x) * bhi(vb.x), bhi(vc.x), acc0);
                acc0 = fmaf(blo(va.y) * blo(vb.y), blo(vc.y), acc0);
                acc0 = fmaf(bhi(va.y) * bhi(vb.y), bhi(vc.y), acc0);
                acc0 = fmaf(blo(va.z) * blo(vb.z), blo(vc.z), acc0);
                acc0 = fmaf(bhi(va.z) * bhi(vb.z), bhi(vc.z), acc0);
                acc0 = fmaf(blo(va.w) * blo(vb.w), blo(vc.w), acc0);
                acc0 = fmaf(bhi(va.w) * bhi(vb.w), bhi(vc.w), acc0);
            }
            {
                const uint4 va = *(const uint4*)(smem + TAB_OFF + baseb[1][0] + (gb ^ swzb[1][0]));
                const uint4 vb = *(const uint4*)(smem + TAB_OFF + baseb[1][1] + (gb ^ swzb[1][1]));
                const uint4 vc = *(const uint4*)(smem + TAB_OFF + baseb[1][2] + (gb ^ swzb[1][2]));
                acc1 = fmaf(blo(va.x) * blo(vb.x), blo(vc.x), acc1);
                acc1 = fmaf(bhi(va.x) * bhi(vb.x), bhi(vc.x), acc1);
                acc1 = fmaf(blo(va.y) * blo(vb.y), blo(vc.y), acc1);
                acc1 = fmaf(bhi(va.y) * bhi(vb.y), bhi(vc.y), acc1);
                acc1 = fmaf(blo(va.z) * blo(vb.z), blo(vc.z), acc1);
                acc1 = fmaf(bhi(va.z) * bhi(vb.z), bhi(vc.z), acc1);
                acc1 = fmaf(blo(va.w) * blo(vb.w), blo(vc.w), acc1);
                acc1 = fmaf(bhi(va.w) * bhi(vb.w), bhi(vc.w), acc1);
            }
        }

        LGKM0(); SCHED0(); SBAR(); SCHED0();   // table consumed -> free for next macro
    }

    if (ATOMIC) {
        atomicAdd(outp + q0,     acc0 * (1.0f / N_DIM));
        atomicAdd(outp + q0 + 1, acc1 * (1.0f / N_DIM));
    } else {
        outp[(size_t)bid * Q_DIM + q0]     = acc0;
        outp[(size_t)bid * Q_DIM + q0 + 1] = acc1;
    }
}

__global__ __launch_bounds__(256) void rap_reduce(const float* __restrict__ partials,
                                                  float* __restrict__ outp) {
    const int q = blockIdx.x * blockDim.x + threadIdx.x;
    float s0 = 0.f, s1 = 0.f, s2 = 0.f, s3 = 0.f;
#pragma unroll 4
    for (int b = 0; b < NBLK; b += 4) {
        s0 += partials[(size_t)(b + 0) * Q_DIM + q];
        s1 += partials[(size_t)(b + 1) * Q_DIM + q];
        s2 += partials[(size_t)(b + 2) * Q_DIM + q];
        s3 += partials[(size_t)(b + 3) * Q_DIM + q];
    }
    outp[q] = ((s0 + s1) + (s2 + s3)) * (1.0f / N_DIM);
}

extern "C" void kernel_launch(void* const* d_in, const int* in_sizes, int n_in,
                              void* d_out, int out_size, void* d_ws, size_t ws_size,
                              hipStream_t stream) {
    const float* W    = (const float*)d_in[0];
    const int*   qidx = (const int*)d_in[1];
    float*       outp = (float*)d_out;

    const size_t need = (size_t)NBLK * Q_DIM * sizeof(float);
    if (ws_size >= need) {
        (void)hipFuncSetAttribute((const void*)rap_main<false>,
                                  hipFuncAttributeMaxDynamicSharedMemorySize, LDS_TOTAL);
        float* partials = (float*)d_ws;
        hipLaunchKernelGGL(rap_main<false>, dim3(NBLK), dim3(TPB), LDS_TOTAL, stream,
                           W, qidx, partials);
        hipLaunchKernelGGL(rap_reduce, dim3(Q_DIM / 256), dim3(256), 0, stream,
                           partials, outp);
    } else {
        (void)hipFuncSetAttribute((const void*)rap_main<true>,
                                  hipFuncAttributeMaxDynamicSharedMemorySize, LDS_TOTAL);
        (void)hipMemsetAsync(d_out, 0, Q_DIM * sizeof(float), stream);
        hipLaunchKernelGGL(rap_main<true>, dim3(NBLK), dim3(TPB), LDS_TOTAL, stream,
                           W, qidx, outp);
    }
}

// Round 7
// 92.773 us; speedup vs baseline: 1.3683x; 1.3683x over previous
//
#include <hip/hip_runtime.h>
#include <stdint.h>

#define D_DIM 1024
#define N_DIM 65536
#define Q_DIM 2048
#define K_DIM 3

#define NBLK  256            // one block per CU
#define TPB   1024           // 16 waves
#define MACW  32             // cols per macro (compute granularity)
#define NMAC  8              // macros per block -> 256 cols
#define NQT   32             // total stage-quarters (NMAC * 4)
#define QROWS 256            // rows per quarter (one quarter = 256 rows x 128 B = 32 KB)

// LDS map (dynamic):
#define RAW_OFF   0          // 2 x 32768 B raw f32 quarter buffers (dbuf)
#define SUMS_OFF  65536      // 16 groups x 32 cols f32 reciprocals = 2048 B (per wave slice)
#define TAB_OFF   67584      // bf16 table [1024 rows][32 cols] = 65536 B, granule-swizzled
#define LDS_TOTAL 133120

#define VMCNT2() asm volatile("s_waitcnt vmcnt(2)" ::: "memory")
#define VMCNT0() asm volatile("s_waitcnt vmcnt(0)" ::: "memory")
#define LGKM0()  asm volatile("s_waitcnt lgkmcnt(0)" ::: "memory")
#define SCHED0() __builtin_amdgcn_sched_barrier(0)
#define SBAR()   __builtin_amdgcn_s_barrier()

typedef const __attribute__((address_space(1))) uint32_t  glb_u32;
typedef __attribute__((address_space(3))) uint32_t        lds_u32;

// round-to-nearest-even f32 -> bf16 (positive normal probs)
__device__ __forceinline__ uint32_t f2bf(float f) {
    uint32_t u = __float_as_uint(f);
    return (u + 0x7fffu + ((u >> 16) & 1u)) >> 16;
}
__device__ __forceinline__ float blo(uint32_t u) { return __uint_as_float(u << 16); }
__device__ __forceinline__ float bhi(uint32_t u) { return __uint_as_float(u & 0xffff0000u); }

// DMA one quarter (256 rows x 128 B) into raw slot (c&1). Wave w stages rows
// [w*16, w*16+16): 2 insts x (8 rows x full 128-B row span). MACRO-MAJOR
// column map: macro m's windows of all 256 blocks tile one contiguous 32-KB
// span of every row (col0 = m*32KB + bid*128B) -> dense DRAM-page use by
// concurrent CUs (R5's bid-major map left pages 12.5% utilized per open).
// Raw buffer XOR-swizzled (16-B granule key r&7) via pre-swizzled global col.
__device__ __forceinline__ void stage_quarter(const float* __restrict__ W, char* smem,
                                              int c, int bid, int w, int l) {
    const int slot  = (c & 1) << 15;
    const int col0  = (c >> 2) * (MACW * NBLK) + bid * MACW;   // floats; macro-major
    const int gsrc  = ((l & 7) ^ ((l >> 3) & 7)) << 2;         // swizzled col offset (floats)
    const int d0    = (c & 3) * QROWS + w * 16 + (l >> 3);     // global row, inst 0
    const float* g0 = W + ((size_t)d0 << 16) + col0 + gsrc;
    const float* g1 = W + ((size_t)(d0 + 8) << 16) + col0 + gsrc;
    __builtin_amdgcn_global_load_lds((glb_u32*)g0, (lds_u32*)(smem + slot + w * 2048),        16, 0, 0);
    __builtin_amdgcn_global_load_lds((glb_u32*)g1, (lds_u32*)(smem + slot + w * 2048 + 1024), 16, 0, 0);
}

template<bool ATOMIC>
__global__ __launch_bounds__(TPB, 4) void rap_main(const float* __restrict__ W,
                                                   const int* __restrict__ qidx,
                                                   float* __restrict__ outp) {
    extern __shared__ char smem[];
    const int tid = threadIdx.x;
    const int bid = blockIdx.x;
    const int w = tid >> 6, l = tid & 63;

    // ---- per-thread query constants (2 queries/thread) ----
    const int q0 = tid * 2;
    int baseb[2][K_DIM];   // d*64 : byte base of table row
    int swzb[2][K_DIM];    // ((d>>1)&3)<<4 : granule XOR key in bytes
#pragma unroll
    for (int qq = 0; qq < 2; ++qq) {
#pragma unroll
        for (int k = 0; k < K_DIM; ++k) {
            const int d = qidx[(q0 + qq) * K_DIM + k];
            baseb[qq][k] = d << 6;
            swzb[qq][k]  = ((d >> 1) & 3) << 4;
        }
    }

    // pass-1 mapping: lane -> (col, bin-half) within wave w's 16-row group
    const int c_col = l >> 1;          // 0..31
    const int h     = l & 1;           // 0..1
    // pass-2 mapping: lane -> (row within wave slice, granule pair)
    const int rr2 = w * 16 + (l >> 2); // quarter-local row 0..255
    const int gp  = l & 3;             // 8-col pair -> table granule

    float acc0 = 0.f, acc1 = 0.f;

    // drain setup loads so vmcnt counts only stage DMAs
    VMCNT0(); SCHED0();
    stage_quarter(W, smem, 0, bid, w, l);
    stage_quarter(W, smem, 1, bid, w, l);

    for (int m = 0; m < NMAC; ++m) {
#pragma unroll
        for (int s = 0; s < 4; ++s) {
            const int c = m * 4 + s;
            if (c == NQT - 1) { VMCNT0(); } else { VMCNT2(); }
            SCHED0();
            const int slot = (c & 1) << 15;

            // ---- pass 1: reciprocal softmax denominators (wave-local group w) ----
            {
                float sum = 0.f;
#pragma unroll
                for (int j = 0; j < 8; ++j) {
                    const float v = *(const float*)(smem + slot + (w * 16 + h * 8 + j) * 128
                                                    + (((c_col >> 2) ^ j) << 4) + (c_col & 3) * 4);
                    sum += __expf(v);
                }
                sum += __shfl_xor(sum, 1);
                const float rec = __builtin_amdgcn_rcpf(sum);
                if (h == 0)
                    *(float*)(smem + SUMS_OFF + w * 128 + c_col * 4) = rec;
            }
            LGKM0(); SCHED0();

            // ---- pass 2: read own row span + recs ----
            const int pg0 = (2 * gp) ^ (rr2 & 7);
            const uint4 rawA = *(const uint4*)(smem + slot + rr2 * 128 + (pg0 << 4));
            const uint4 rawB = *(const uint4*)(smem + slot + rr2 * 128 + ((pg0 ^ 1) << 4));
            const float4 rc0 = *(const float4*)(smem + SUMS_OFF + w * 128 + gp * 32);
            const float4 rc1 = *(const float4*)(smem + SUMS_OFF + w * 128 + gp * 32 + 16);
            LGKM0(); SCHED0();

            // raw slot fully consumed by this wave -> refill it early
            if (c + 2 < NQT) stage_quarter(W, smem, c + 2, bid, w, l);
            SCHED0();

            // ---- pass 2: normalize, pack bf16, write table ----
            {
                const float* fA = (const float*)&rawA;
                const float* fB = (const float*)&rawB;
                uint4 pk;
                pk.x = f2bf(__expf(fA[0]) * rc0.x) | (f2bf(__expf(fA[1]) * rc0.y) << 16);
                pk.y = f2bf(__expf(fA[2]) * rc0.z) | (f2bf(__expf(fA[3]) * rc0.w) << 16);
                pk.z = f2bf(__expf(fB[0]) * rc1.x) | (f2bf(__expf(fB[1]) * rc1.y) << 16);
                pk.w = f2bf(__expf(fB[2]) * rc1.z) | (f2bf(__expf(fB[3]) * rc1.w) << 16);
                const int row_d = (c & 3) * QROWS + rr2;
                *(uint4*)(smem + TAB_OFF + row_d * 64 + ((gp ^ ((row_d >> 1) & 3)) << 4)) = pk;
            }
        }

        LGKM0(); SCHED0(); SBAR(); SCHED0();   // table published

        // ---- compute: 2 queries x 4 granules x 8 cols ----
#pragma unroll
        for (int g16 = 0; g16 < 4; ++g16) {
            const int gb = g16 << 4;
            {
                const uint4 va = *(const uint4*)(smem + TAB_OFF + baseb[0][0] + (gb ^ swzb[0][0]));
                const uint4 vb = *(const uint4*)(smem + TAB_OFF + baseb[0][1] + (gb ^ swzb[0][1]));
                const uint4 vc = *(const uint4*)(smem + TAB_OFF + baseb[0][2] + (gb ^ swzb[0][2]));
                acc0 = fmaf(blo(va.x) * blo(vb.x), blo(vc.x), acc0);
                acc0 = fmaf(bhi(va.x) * bhi(vb.x), bhi(vc.x), acc0);
                acc0 = fmaf(blo(va.y) * blo(vb.y), blo(vc.y), acc0);
                acc0 = fmaf(bhi(va.y) * bhi(vb.y), bhi(vc.y), acc0);
                acc0 = fmaf(blo(va.z) * blo(vb.z), blo(vc.z), acc0);
                acc0 = fmaf(bhi(va.z) * bhi(vb.z), bhi(vc.z), acc0);
                acc0 = fmaf(blo(va.w) * blo(vb.w), blo(vc.w), acc0);
                acc0 = fmaf(bhi(va.w) * bhi(vb.w), bhi(vc.w), acc0);
            }
            {
                const uint4 va = *(const uint4*)(smem + TAB_OFF + baseb[1][0] + (gb ^ swzb[1][0]));
                const uint4 vb = *(const uint4*)(smem + TAB_OFF + baseb[1][1] + (gb ^ swzb[1][1]));
                const uint4 vc = *(const uint4*)(smem + TAB_OFF + baseb[1][2] + (gb ^ swzb[1][2]));
                acc1 = fmaf(blo(va.x) * blo(vb.x), blo(vc.x), acc1);
                acc1 = fmaf(bhi(va.x) * bhi(vb.x), bhi(vc.x), acc1);
                acc1 = fmaf(blo(va.y) * blo(vb.y), blo(vc.y), acc1);
                acc1 = fmaf(bhi(va.y) * bhi(vb.y), bhi(vc.y), acc1);
                acc1 = fmaf(blo(va.z) * blo(vb.z), blo(vc.z), acc1);
                acc1 = fmaf(bhi(va.z) * bhi(vb.z), bhi(vc.z), acc1);
                acc1 = fmaf(blo(va.w) * blo(vb.w), blo(vc.w), acc1);
                acc1 = fmaf(bhi(va.w) * bhi(vb.w), bhi(vc.w), acc1);
            }
        }

        LGKM0(); SCHED0(); SBAR(); SCHED0();   // table consumed -> free for next macro
    }

    if (ATOMIC) {
        atomicAdd(outp + q0,     acc0 * (1.0f / N_DIM));
        atomicAdd(outp + q0 + 1, acc1 * (1.0f / N_DIM));
    } else {
        outp[(size_t)bid * Q_DIM + q0]     = acc0;
        outp[(size_t)bid * Q_DIM + q0 + 1] = acc1;
    }
}

__global__ __launch_bounds__(256) void rap_reduce(const float* __restrict__ partials,
                                                  float* __restrict__ outp) {
    const int q = blockIdx.x * blockDim.x + threadIdx.x;
    float s0 = 0.f, s1 = 0.f, s2 = 0.f, s3 = 0.f;
#pragma unroll 4
    for (int b = 0; b < NBLK; b += 4) {
        s0 += partials[(size_t)(b + 0) * Q_DIM + q];
        s1 += partials[(size_t)(b + 1) * Q_DIM + q];
        s2 += partials[(size_t)(b + 2) * Q_DIM + q];
        s3 += partials[(size_t)(b + 3) * Q_DIM + q];
    }
    outp[q] = ((s0 + s1) + (s2 + s3)) * (1.0f / N_DIM);
}

extern "C" void kernel_launch(void* const* d_in, const int* in_sizes, int n_in,
                              void* d_out, int out_size, void* d_ws, size_t ws_size,
                              hipStream_t stream) {
    const float* W    = (const float*)d_in[0];
    const int*   qidx = (const int*)d_in[1];
    float*       outp = (float*)d_out;

    const size_t need = (size_t)NBLK * Q_DIM * sizeof(float);
    if (ws_size >= need) {
        (void)hipFuncSetAttribute((const void*)rap_main<false>,
                                  hipFuncAttributeMaxDynamicSharedMemorySize, LDS_TOTAL);
        float* partials = (float*)d_ws;
        hipLaunchKernelGGL(rap_main<false>, dim3(NBLK), dim3(TPB), LDS_TOTAL, stream,
                           W, qidx, partials);
        hipLaunchKernelGGL(rap_reduce, dim3(Q_DIM / 256), dim3(256), 0, stream,
                           partials, outp);
    } else {
        (void)hipFuncSetAttribute((const void*)rap_main<true>,
                                  hipFuncAttributeMaxDynamicSharedMemorySize, LDS_TOTAL);
        (void)hipMemsetAsync(d_out, 0, Q_DIM * sizeof(float), stream);
        hipLaunchKernelGGL(rap_main<true>, dim3(NBLK), dim3(TPB), LDS_TOTAL, stream,
                           W, qidx, outp);
    }
}